// Round 2
// baseline (534.971 us; speedup 1.0000x reference)
//
#include <hip/hip_runtime.h>
#include <math.h>

#define N_NODES 100000
#define N_EDGES 1600000
#define F_IN    500
#define HIDDEN  64
#define N_CLASS 40
#define KPAD    512

#define NB   2048      // dst buckets
#define NPB  49        // nodes per bucket (2048*49 = 100352 >= N)
#define EPB  16384     // edges per block in bhist/bfill
#define CAP  1536      // LDS pair capacity in k_bucket_csr

typedef __attribute__((ext_vector_type(4))) float f32x4;
typedef __attribute__((ext_vector_type(8))) __bf16 bf16x8;

__device__ __forceinline__ unsigned short f2bf(float f) {
    unsigned int u = __float_as_uint(f);
    u = (u + 0x7FFF + ((u >> 16) & 1)) >> 16;   // RNE
    return (unsigned short)u;
}
__device__ __forceinline__ float bfu_lo(unsigned int v) {   // low ushort -> float
    return __uint_as_float(v << 16);
}
__device__ __forceinline__ float bfu_hi(unsigned int v) {   // high ushort -> float
    return __uint_as_float(v & 0xFFFF0000u);
}

// W1t[n][k] = bf16(W1[k][n]), k zero-padded to 512; also zeroes bcnt (merged launch)
__global__ void k_prep_w1t(const float* __restrict__ w1, unsigned short* __restrict__ w1t,
                           int* __restrict__ bcnt) {
    int idx = blockIdx.x * blockDim.x + threadIdx.x;
    if (idx < NB) bcnt[idx] = 0;
    if (idx >= HIDDEN * KPAD) return;
    int n = idx >> 9, k = idx & (KPAD - 1);
    float v = (k < F_IN) ? w1[k * HIDDEN + n] : 0.f;
    w1t[idx] = f2bf(v);
}

// ---------- CSR build: bucketed counting sort ----------
__launch_bounds__(1024)
__global__ void k_bhist(const int* __restrict__ dst, int* __restrict__ bcnt, int e) {
    __shared__ int h[NB];
    for (int i = threadIdx.x; i < NB; i += 1024) h[i] = 0;
    __syncthreads();
    int base = blockIdx.x * EPB;
#pragma unroll
    for (int j = 0; j < 16; ++j) {
        int i = base + j * 1024 + threadIdx.x;
        if (i < e) atomicAdd(&h[dst[i] / NPB], 1);
    }
    __syncthreads();
    for (int i = threadIdx.x; i < NB; i += 1024)
        if (h[i]) atomicAdd(&bcnt[i], h[i]);
}

__launch_bounds__(1024)
__global__ void k_bscan(const int* __restrict__ bcnt, int* __restrict__ bptr,
                        int* __restrict__ bcur) {
    __shared__ int s[1024];
    int t = threadIdx.x;
    int a = bcnt[2 * t], b = bcnt[2 * t + 1];
    int v = a + b;
    s[t] = v;
    __syncthreads();
    for (int off = 1; off < 1024; off <<= 1) {
        int u = (t >= off) ? s[t - off] : 0;
        __syncthreads();
        s[t] += u;
        __syncthreads();
    }
    int excl = s[t] - v;
    bptr[2 * t] = excl;     bptr[2 * t + 1] = excl + a;
    bcur[2 * t] = excl;     bcur[2 * t + 1] = excl + a;
    if (t == 1023) bptr[NB] = s[1023];
}

__launch_bounds__(1024)
__global__ void k_bfill(const int* __restrict__ src, const int* __restrict__ dst,
                        int* __restrict__ bcur, int2* __restrict__ ebuf, int e) {
    __shared__ int hist[NB];
    __shared__ int base_[NB];
    for (int i = threadIdx.x; i < NB; i += 1024) hist[i] = 0;
    __syncthreads();
    int b0 = blockIdx.x * EPB;
    int s_[16], d_[16];
#pragma unroll
    for (int j = 0; j < 16; ++j) {
        int i = b0 + j * 1024 + threadIdx.x;
        if (i < e) {
            s_[j] = src[i];
            d_[j] = dst[i];
            atomicAdd(&hist[d_[j] / NPB], 1);
        } else d_[j] = -1;
    }
    __syncthreads();
    for (int i = threadIdx.x; i < NB; i += 1024) {
        int hc = hist[i];
        base_[i] = hc ? atomicAdd(&bcur[i], hc) : 0;
        hist[i] = 0;    // reuse as local cursor
    }
    __syncthreads();
#pragma unroll
    for (int j = 0; j < 16; ++j) {
        if (d_[j] >= 0) {
            int bu = d_[j] / NPB;
            int r = atomicAdd(&hist[bu], 1);
            ebuf[base_[bu] + r] = make_int2(s_[j], d_[j]);
        }
    }
}

__launch_bounds__(256)
__global__ void k_bucket_csr(const int2* __restrict__ ebuf, const int* __restrict__ bptr,
                             int* __restrict__ rp, int* __restrict__ col,
                             float* __restrict__ dinv, int n) {
    int b  = blockIdx.x;
    int lo = b * NPB;
    if (lo >= n) return;
    int hi  = min(lo + NPB, n);
    int eb0 = bptr[b], ec = bptr[b + 1] - eb0;

    __shared__ int2 pairs[CAP];
    __shared__ int  hist[NPB];
    __shared__ int  excl[NPB + 1];
    for (int j = threadIdx.x; j < NPB; j += 256) hist[j] = 0;
    __syncthreads();
    for (int i = threadIdx.x; i < ec; i += 256) {
        int2 p = ebuf[eb0 + i];
        if (i < CAP) pairs[i] = p;
        atomicAdd(&hist[p.y - lo], 1);
    }
    __syncthreads();
    if (threadIdx.x == 0) {
        int acc = 0;
        for (int j = 0; j < NPB; ++j) { excl[j] = acc; acc += hist[j]; }
        excl[NPB] = acc;
    }
    __syncthreads();
    for (int j = threadIdx.x; j < hi - lo; j += 256) {
        rp[lo + j]   = eb0 + excl[j];
        dinv[lo + j] = rsqrtf((float)(hist[j] + 1));   // +1 self loop
    }
    if (hi == n && threadIdx.x == 0) rp[n] = eb0 + ec;
    __syncthreads();
    for (int j = threadIdx.x; j < NPB; j += 256) hist[j] = 0;  // reuse as cursor
    __syncthreads();
    for (int i = threadIdx.x; i < ec; i += 256) {
        int2 p  = (i < CAP) ? pairs[i] : ebuf[eb0 + i];
        int  li = p.y - lo;
        int  r  = atomicAdd(&hist[li], 1);
        col[eb0 + excl[li] + r] = p.x;
    }
}

// ---------- GEMM1: hs[N,64](bf16, pre-scaled by dinv) = dinv * (x @ W1) ----------
// Wave-private double-buffered LDS tile, NO barriers (DS ops are in-order per
// wave; compiler orders may-alias LDS ops), 1-deep register prefetch so the
// next K-slice's HBM loads are in flight during the current MFMAs.
__launch_bounds__(256)
__global__ void k_gemm1(const float* __restrict__ x, const unsigned short* __restrict__ w1t,
                        const float* __restrict__ dinv, unsigned short* __restrict__ hs, int n) {
    __shared__ __align__(16) unsigned short xs[4][2][32][40];   // 20.5 KB
    const int tid  = threadIdx.x;
    const int wave = tid >> 6;
    const int lane = tid & 63;
    const int quad = lane >> 4;
    const int l16  = lane & 15;
    const int rowb = blockIdx.x * 128 + wave * 32;

    const int srow = lane >> 3;
    const int skof = (lane & 7) * 4;

    f32x4 acc[2][4];
#pragma unroll
    for (int rt = 0; rt < 2; ++rt)
#pragma unroll
        for (int ct = 0; ct < 4; ++ct) acc[rt][ct] = (f32x4)0.f;

    auto LOAD = [&](float4 (&t)[4], int ks) {
        const int k0 = ks * 32;
        if (ks < 15) {
#pragma unroll
            for (int u = 0; u < 4; ++u) {
                int grow = rowb + u * 8 + srow;
                t[u] = (grow < n) ? *(const float4*)&x[(size_t)grow * F_IN + k0 + skof]
                                  : make_float4(0.f, 0.f, 0.f, 0.f);
            }
        } else {
#pragma unroll
            for (int u = 0; u < 4; ++u) {
                int grow = rowb + u * 8 + srow;
                const float* p = &x[(size_t)grow * F_IN];
                float v0 = (grow < n && k0 + skof + 0 < F_IN) ? p[k0 + skof + 0] : 0.f;
                float v1 = (grow < n && k0 + skof + 1 < F_IN) ? p[k0 + skof + 1] : 0.f;
                float v2 = (grow < n && k0 + skof + 2 < F_IN) ? p[k0 + skof + 2] : 0.f;
                float v3 = (grow < n && k0 + skof + 3 < F_IN) ? p[k0 + skof + 3] : 0.f;
                t[u] = make_float4(v0, v1, v2, v3);
            }
        }
    };
    auto STASH = [&](const float4 (&t)[4], int buf) {
#pragma unroll
        for (int u = 0; u < 4; ++u) {
            unsigned int lo = (unsigned int)f2bf(t[u].x) | ((unsigned int)f2bf(t[u].y) << 16);
            unsigned int hi = (unsigned int)f2bf(t[u].z) | ((unsigned int)f2bf(t[u].w) << 16);
            *(uint2*)&xs[wave][buf][u * 8 + srow][skof] = make_uint2(lo, hi);
        }
    };

    float4 tcur[4], tnx[4];
    LOAD(tcur, 0);
    STASH(tcur, 0);
    for (int ks = 0; ks < 16; ++ks) {
        const int buf = ks & 1;
        if (ks < 15) LOAD(tnx, ks + 1);          // issue early: in flight during MFMA
        const int k0 = ks * 32;
        bf16x8 bfrag[4];
#pragma unroll
        for (int ct = 0; ct < 4; ++ct)
            bfrag[ct] = *(const bf16x8*)&w1t[(ct * 16 + l16) * KPAD + k0 + quad * 8];
        bf16x8 af[2];
#pragma unroll
        for (int rt = 0; rt < 2; ++rt)
            af[rt] = *(const bf16x8*)&xs[wave][buf][rt * 16 + l16][quad * 8];
#pragma unroll
        for (int rt = 0; rt < 2; ++rt)
#pragma unroll
            for (int ct = 0; ct < 4; ++ct)
                acc[rt][ct] = __builtin_amdgcn_mfma_f32_16x16x32_bf16(
                    af[rt], bfrag[ct], acc[rt][ct], 0, 0, 0);
        if (ks < 15) STASH(tnx, buf ^ 1);        // write other buffer; no barrier
    }

    // D layout: row = quad*4 + reg, col = lane&15 ; store bf16 * dinv[row]
#pragma unroll
    for (int rt = 0; rt < 2; ++rt) {
#pragma unroll
        for (int reg = 0; reg < 4; ++reg) {
            int grow = rowb + rt * 16 + quad * 4 + reg;
            if (grow < n) {
                float dv = dinv[grow];
#pragma unroll
                for (int ct = 0; ct < 4; ++ct)
                    hs[(size_t)grow * HIDDEN + ct * 16 + l16] = f2bf(dv * acc[rt][ct][reg]);
            }
        }
    }
}

// ---------- aggregation over pre-scaled bf16 table ----------
// out[i] = dinv[i] * (sum_e hs[col[e]] + hs[i]) + b  (+ReLU / +log_softmax)
// 8 edge streams per wave (8-lane groups), uint4 (8 bf16 feats) per lane.
// Main loop: 32 edges / 32 gathers in flight. Tail: <=3 predicated gathers,
// all independent -> one L2/L3 round trip for the typical degree-16 node.
// FUSE: layer-2 GEMM (row[64] @ W2[64x40]) fused into the epilogue via a
// wave-private LDS row buffer (no cross-wave sync needed).
template <int F, bool RELU, bool LSM, bool FUSE>
__launch_bounds__(256)
__global__ void k_agg(const uint4* __restrict__ hs4, const int* __restrict__ rp,
                      const int* __restrict__ col, const float* __restrict__ dinv,
                      const float* __restrict__ bias, float* __restrict__ outf,
                      unsigned short* __restrict__ outh, const float* __restrict__ w2,
                      int n) {
    constexpr int PW4 = (F + 7) / 8;   // uint4 per row: F=64 -> 8, F=40 -> 5
    __shared__ float ws2[FUSE ? HIDDEN * N_CLASS : 1];
    __shared__ float rowbuf[FUSE ? 4 : 1][FUSE ? HIDDEN : 1];
    if constexpr (FUSE) {
        for (int i = threadIdx.x; i < HIDDEN * N_CLASS; i += 256) ws2[i] = w2[i];
        __syncthreads();
    }
    const int lane = threadIdx.x & 63;
    const int wave = threadIdx.x >> 6;
    const int q    = lane >> 3;    // edge-stream id 0..7
    const int p    = lane & 7;     // uint4 slot within stream
    const bool act = p < PW4;
    int wid = __builtin_amdgcn_readfirstlane((blockIdx.x * blockDim.x + threadIdx.x) >> 6);
    const int nw = (gridDim.x * blockDim.x) >> 6;
    const uint4 z = make_uint4(0u, 0u, 0u, 0u);

    for (; wid < n; wid += nw) {
        const int beg = rp[wid], end = rp[wid + 1];
        float a[8];
#pragma unroll
        for (int i = 0; i < 8; ++i) a[i] = 0.f;
        auto ACC = [&](uint4 v) {
            a[0] += bfu_lo(v.x); a[1] += bfu_hi(v.x);
            a[2] += bfu_lo(v.y); a[3] += bfu_hi(v.y);
            a[4] += bfu_lo(v.z); a[5] += bfu_hi(v.z);
            a[6] += bfu_lo(v.w); a[7] += bfu_hi(v.w);
        };
        int e = beg + q;
        for (; e + 24 < end; e += 32) {          // 32 edges/wave-iter
            int c0 = col[e], c1 = col[e + 8], c2 = col[e + 16], c3 = col[e + 24];
            uint4 v0 = act ? hs4[(unsigned)c0 * PW4 + p] : z;
            uint4 v1 = act ? hs4[(unsigned)c1 * PW4 + p] : z;
            uint4 v2 = act ? hs4[(unsigned)c2 * PW4 + p] : z;
            uint4 v3 = act ? hs4[(unsigned)c3 * PW4 + p] : z;
            ACC(v0); ACC(v1); ACC(v2); ACC(v3);
        }
        {   // single-shot predicated tail: <=3 edges/stream, all independent
            const bool g0 = e < end, g1 = e + 8 < end, g2 = e + 16 < end;
            int c0 = g0 ? col[e] : 0;
            int c1 = g1 ? col[e + 8] : 0;
            int c2 = g2 ? col[e + 16] : 0;
            uint4 v0 = (act && g0) ? hs4[(unsigned)c0 * PW4 + p] : z;
            uint4 v1 = (act && g1) ? hs4[(unsigned)c1 * PW4 + p] : z;
            uint4 v2 = (act && g2) ? hs4[(unsigned)c2 * PW4 + p] : z;
            ACC(v0); ACC(v1); ACC(v2);
        }
        // combine the 8 stream partials
#pragma unroll
        for (int i = 0; i < 8; ++i) {
            a[i] += __shfl_xor(a[i], 8);
            a[i] += __shfl_xor(a[i], 16);
            a[i] += __shfl_xor(a[i], 32);
        }

        const float di = dinv[wid];
        uint4 sv = act ? hs4[(unsigned)wid * PW4 + p] : z;
        float s[8] = {bfu_lo(sv.x), bfu_hi(sv.x), bfu_lo(sv.y), bfu_hi(sv.y),
                      bfu_lo(sv.z), bfu_hi(sv.z), bfu_lo(sv.w), bfu_hi(sv.w)};
        float bv[8];
        if (act) {
            float4 t0 = *(const float4*)&bias[8 * p];
            float4 t1 = *(const float4*)&bias[8 * p + 4];
            bv[0] = t0.x; bv[1] = t0.y; bv[2] = t0.z; bv[3] = t0.w;
            bv[4] = t1.x; bv[5] = t1.y; bv[6] = t1.z; bv[7] = t1.w;
        } else {
#pragma unroll
            for (int i = 0; i < 8; ++i) bv[i] = 0.f;
        }
        float r[8];
#pragma unroll
        for (int i = 0; i < 8; ++i) {
            r[i] = di * (a[i] + s[i]) + bv[i];
            if (RELU) r[i] = fmaxf(r[i], 0.f);
        }
        if constexpr (LSM) {
            float m = -INFINITY;
            if (act) {
#pragma unroll
                for (int i = 0; i < 8; ++i) m = fmaxf(m, r[i]);
            }
#pragma unroll
            for (int off = 4; off; off >>= 1) m = fmaxf(m, __shfl_xor(m, off));
            float ex = 0.f;
            if (act) {
#pragma unroll
                for (int i = 0; i < 8; ++i) ex += __expf(r[i] - m);
            }
#pragma unroll
            for (int off = 4; off; off >>= 1) ex += __shfl_xor(ex, off);
            float lse = m + __logf(ex);
#pragma unroll
            for (int i = 0; i < 8; ++i) r[i] -= lse;
        }
        if constexpr (FUSE) {
            // stash the fp32 row (wave-private; DS in-order per wave)
            if (q == 0 && act) {
                *(float4*)&rowbuf[wave][8 * p]     = make_float4(r[0], r[1], r[2], r[3]);
                *(float4*)&rowbuf[wave][8 * p + 4] = make_float4(r[4], r[5], r[6], r[7]);
            }
            if (lane < N_CLASS) {
                float y = 0.f;
#pragma unroll
                for (int k = 0; k < HIDDEN; k += 4) {
                    float4 rv = *(const float4*)&rowbuf[wave][k];   // broadcast
                    y = fmaf(rv.x, ws2[(k + 0) * N_CLASS + lane], y);
                    y = fmaf(rv.y, ws2[(k + 1) * N_CLASS + lane], y);
                    y = fmaf(rv.z, ws2[(k + 2) * N_CLASS + lane], y);
                    y = fmaf(rv.w, ws2[(k + 3) * N_CLASS + lane], y);
                }
                outh[(size_t)wid * N_CLASS + lane] = f2bf(di * y);
            }
        } else {
            if (q == 0 && act) {
                *(float4*)&outf[(size_t)wid * F + 8 * p]     = make_float4(r[0], r[1], r[2], r[3]);
                *(float4*)&outf[(size_t)wid * F + 8 * p + 4] = make_float4(r[4], r[5], r[6], r[7]);
            }
        }
    }
}

extern "C" void kernel_launch(void* const* d_in, const int* in_sizes, int n_in,
                              void* d_out, int out_size, void* d_ws, size_t ws_size,
                              hipStream_t stream) {
    const float* x   = (const float*)d_in[0];
    const float* W1  = (const float*)d_in[1];
    const float* b1  = (const float*)d_in[2];
    const float* W2  = (const float*)d_in[3];
    const float* b2  = (const float*)d_in[4];
    const int*   ei  = (const int*)d_in[5];
    const int*   src = ei;
    const int*   dst = ei + N_EDGES;
    float*       out = (float*)d_out;

    char*  ws  = (char*)d_ws;
    size_t off = 0;
    auto alloc = [&](size_t bytes) -> void* {
        void* p = ws + off;
        off += (bytes + 255) & ~(size_t)255;
        return p;
    };
    int*            bcnt = (int*)alloc((size_t)NB * 4);
    int*            bptr = (int*)alloc((size_t)(NB + 1) * 4);
    int*            bcur = (int*)alloc((size_t)NB * 4);
    int*            rp   = (int*)alloc((size_t)(N_NODES + 1) * 4);
    int*            col  = (int*)alloc((size_t)N_EDGES * 4);
    float*          dinv = (float*)alloc((size_t)N_NODES * 4);
    unsigned short* w1t  = (unsigned short*)alloc((size_t)HIDDEN * KPAD * 2);
    unsigned short* h1s  = (unsigned short*)alloc((size_t)N_NODES * HIDDEN * 2);  // bf16, pre-scaled
    int2*           ebuf = (int2*)alloc((size_t)N_EDGES * 8);
    unsigned short* h2s  = (unsigned short*)ebuf;   // bf16 [N][40]; ebuf dead after k_bucket_csr

    const int NBH = (N_EDGES + EPB - 1) / EPB;   // 98

    // CSR build (bucketed counting sort) + W1^T prep (also zeroes bcnt)
    k_prep_w1t<<<(HIDDEN * KPAD + 255) / 256, 256, 0, stream>>>(W1, w1t, bcnt);
    k_bhist<<<NBH, 1024, 0, stream>>>(dst, bcnt, N_EDGES);
    k_bscan<<<1, 1024, 0, stream>>>(bcnt, bptr, bcur);
    k_bfill<<<NBH, 1024, 0, stream>>>(src, dst, bcur, ebuf, N_EDGES);
    k_bucket_csr<<<NB, 256, 0, stream>>>(ebuf, bptr, rp, col, dinv, N_NODES);

    // layer 1: GEMM1 then aggregation with fused layer-2 GEMM in the epilogue
    k_gemm1<<<(N_NODES + 127) / 128, 256, 0, stream>>>(x, w1t, dinv, h1s, N_NODES);
    k_agg<HIDDEN, true, false, true><<<2048, 256, 0, stream>>>(
        (const uint4*)h1s, rp, col, dinv, b1, nullptr, h2s, W2, N_NODES);

    // layer 2 aggregation (+bias, +fused log_softmax)
    k_agg<N_CLASS, false, true, false><<<2048, 256, 0, stream>>>(
        (const uint4*)h2s, rp, col, dinv, b2, out, nullptr, nullptr, N_NODES);
}